// Round 2
// baseline (205.485 us; speedup 1.0000x reference)
//
#include <hip/hip_runtime.h>
#include <stdint.h>

// Problem constants (fixed by reference setup_inputs)
#define BB 8
#define SS 2048
#define DD 2048
#define EE 8
#define CHUNKS 128
#define ROWS 16   // SS / CHUNKS

typedef float f4 __attribute__((ext_vector_type(4)));

// Kernel 1: stream x (fp32), accumulate per-(b,chunk): partial dot(x_rows, W[e])
// for e<8 and partial sum of x. Emits 9 floats per block into d_ws.
__global__ __launch_bounds__(256) void k_partial(const float* __restrict__ x,
                                                 const float* __restrict__ W,
                                                 float* __restrict__ pout) {
    const int t = threadIdx.x;
    const int bid = blockIdx.x;
    const int b = bid >> 7;        // / CHUNKS
    const int chunk = bid & (CHUNKS - 1);
    const int d0 = t * 8;          // 256 threads * 8 floats = full D row (2048)

    // W fragment in registers: 8 experts x 8 contiguous cols
    float w[8][8];
#pragma unroll
    for (int e = 0; e < 8; ++e) {
        f4 wa = *(const f4*)(W + e * DD + d0);
        f4 wb = *(const f4*)(W + e * DD + d0 + 4);
#pragma unroll
        for (int j = 0; j < 4; ++j) { w[e][j] = wa[j]; w[e][4 + j] = wb[j]; }
    }

    float acc[8] = {0.f, 0.f, 0.f, 0.f, 0.f, 0.f, 0.f, 0.f};
    float xtot = 0.f;

    const float* xp = x + ((size_t)b * SS + (size_t)chunk * ROWS) * DD + d0;
#pragma unroll 4
    for (int r = 0; r < ROWS; ++r) {
        f4 xa = *(const f4*)(xp + (size_t)r * DD);
        f4 xb = *(const f4*)(xp + (size_t)r * DD + 4);
        float xf[8];
#pragma unroll
        for (int j = 0; j < 4; ++j) { xf[j] = xa[j]; xf[4 + j] = xb[j]; }
#pragma unroll
        for (int j = 0; j < 8; ++j) xtot += xf[j];
#pragma unroll
        for (int e = 0; e < 8; ++e) {
#pragma unroll
            for (int j = 0; j < 8; ++j) acc[e] = fmaf(xf[j], w[e][j], acc[e]);
        }
    }

    // wave-level butterfly reduce of 9 values
    float vals[9];
#pragma unroll
    for (int e = 0; e < 8; ++e) vals[e] = acc[e];
    vals[8] = xtot;
#pragma unroll
    for (int off = 32; off >= 1; off >>= 1) {
#pragma unroll
        for (int j = 0; j < 9; ++j) vals[j] += __shfl_xor(vals[j], off, 64);
    }

    __shared__ float lw[4][9];
    const int lane = t & 63, wid = t >> 6;
    if (lane == 0) {
#pragma unroll
        for (int j = 0; j < 9; ++j) lw[wid][j] = vals[j];
    }
    __syncthreads();
    if (t < 9) {
        pout[bid * 9 + t] = lw[0][t] + lw[1][t] + lw[2][t] + lw[3][t];
    }
}

// Kernel 2: single block. Reduce CHUNKS partials per batch, W row stats
// (unbiased std + EPS, keep_init scale), scores + noise, softmax, top-2.
// Writes 96 fp32: combine [8,8] | indices [8,2] (as float) | topk [8,2].
__global__ __launch_bounds__(256) void k_finish(const float* __restrict__ pin,
                                                const float* __restrict__ W,
                                                const float* __restrict__ gain,
                                                const float* __restrict__ istd,
                                                const float* __restrict__ noise,
                                                float* __restrict__ out) {
    const int t = threadIdx.x;
    __shared__ float sdot[BB][9];
    __shared__ float smean[EE], sscale[EE];
    __shared__ float ssum[EE][32], ssq[EE][32];

    // Phase A: reduce partials over CHUNKS (72 threads, one per (b, j))
    if (t < BB * 9) {
        const int b = t / 9, j = t % 9;
        float s = 0.f;
        for (int c = 0; c < CHUNKS; ++c) s += pin[(b * CHUNKS + c) * 9 + j];
        sdot[b][j] = s;
    }

    // Phase B: per-expert sum / sumsq over W rows (32 threads per expert)
    {
        const int e = t >> 5, l = t & 31;
        float s = 0.f, q = 0.f;
        for (int i = 0; i < DD / 32; ++i) {
            float wv = W[e * DD + l + 32 * i];
            s += wv;
            q = fmaf(wv, wv, q);
        }
        ssum[e][l] = s;
        ssq[e][l] = q;
    }
    __syncthreads();

    if (t < EE) {
        float s = 0.f, q = 0.f;
        for (int l = 0; l < 32; ++l) { s += ssum[t][l]; q += ssq[t][l]; }
        const float mean = s / (float)DD;
        float var = (q - (float)DD * mean * mean) / (float)(DD - 1);
        var = fmaxf(var, 0.f);
        const float stdv = sqrtf(var) + 1e-5f;   // torch-style unbiased std + EPS
        smean[t] = mean;
        sscale[t] = istd[t] / stdv * gain[t];
    }
    __syncthreads();

    // Phase C: one thread per batch row: scores -> softmax -> top2 -> outputs
    if (t < BB) {
        const int b = t;
        const float xtot = sdot[b][8];
        float p[EE];
        float m = -1e30f;
#pragma unroll
        for (int e = 0; e < EE; ++e) {
            float sc = sscale[e] * (sdot[b][e] - smean[e] * xtot) * (1.f / (float)SS)
                     + noise[b * EE + e];
            p[e] = sc;
            m = fmaxf(m, sc);
        }
        float sum = 0.f;
#pragma unroll
        for (int e = 0; e < EE; ++e) { p[e] = __expf(p[e] - m); sum += p[e]; }
        const float inv = 1.f / sum;
#pragma unroll
        for (int e = 0; e < EE; ++e) p[e] *= inv;

        // top-2, ties -> lowest index first (strict >, ascending scan)
        int i1 = 0;
#pragma unroll
        for (int e = 1; e < EE; ++e) if (p[e] > p[i1]) i1 = e;
        int i2 = (i1 == 0) ? 1 : 0;
#pragma unroll
        for (int e = 0; e < EE; ++e) if (e != i1 && p[e] > p[i2]) i2 = e;

        // combine tensor [B,E]
#pragma unroll
        for (int e = 0; e < EE; ++e) {
            float v = (e == i1) ? p[i1] : ((e == i2) ? p[i2] : 0.f);
            out[b * EE + e] = v;
        }
        // indices [B,2] as numeric values
        out[64 + b * 2 + 0] = (float)i1;
        out[64 + b * 2 + 1] = (float)i2;
        // topk gate scores [B,2]
        out[80 + b * 2 + 0] = p[i1];
        out[80 + b * 2 + 1] = p[i2];
    }
}

extern "C" void kernel_launch(void* const* d_in, const int* in_sizes, int n_in,
                              void* d_out, int out_size, void* d_ws, size_t ws_size,
                              hipStream_t stream) {
    const float* x     = (const float*)d_in[0];
    const float* W     = (const float*)d_in[1];
    const float* gain  = (const float*)d_in[2];
    const float* istd  = (const float*)d_in[3];
    const float* noise = (const float*)d_in[4];
    // d_in[5] = top_k (==2) — hardcoded per reference.

    float* pbuf = (float*)d_ws;          // BB*CHUNKS*9 floats = 36 KB
    float* out = (float*)d_out;          // 96 fp32

    k_partial<<<dim3(BB * CHUNKS), dim3(256), 0, stream>>>(x, W, pbuf);
    k_finish<<<dim3(1), dim3(256), 0, stream>>>(pbuf, W, gain, istd, noise, out);
}